// Round 11
// baseline (106.750 us; speedup 1.0000x reference)
//
#include <hip/hip_runtime.h>

#define NH 254
#define NSTEP 32
#define NB 256

constexpr float  FEPS = 1e-4f;
constexpr double DDT  = 1.0 / 60.0;
constexpr double DQV  = 200.0;
constexpr double DPQ  = 5.0;
constexpr double DQA  = 1.0;
constexpr double DEPS = 1e-4;

// ---------------------------------------------------------------------------
// ONE dispatch, 256 blocks x 256 threads. Block b owns batch row b and
// REDUNDANTLY computes the whole scalar pipeline (free across idle CUs;
// Lq is L2-resident at 258 KB):
//  T: t = Lq^T Af      (thread=column, 32-deep load batches, triangle skip)
//  G: s_b = sum_i x_b[i]*g_i with g_i = Lq[i,:].t + eps*Af_i fused per row
//     (4 waves x 64 rows, 4-row interleave, wave butterfly reduce)
//  S: fp64 c -> Q_final -> Gauss-Jordan (2 RHS) -> cA/cB  (proven pipeline)
//  O: out[b,i] = gp_b + gv_b*cB_i + s_b*cA_i
// ---------------------------------------------------------------------------
__global__ __launch_bounds__(256) void k_fused(const float* __restrict__ Lq,
                                               const float* __restrict__ Af,
                                               const float* __restrict__ x,
                                               const float* __restrict__ gp,
                                               const float* __restrict__ gv,
                                               float* __restrict__ out) {
    __shared__ float  af_sh[256];
    __shared__ float  x_sh[256];
    __shared__ float  t_sh[256];
    __shared__ float  svals[4];
    __shared__ double red[4];
    __shared__ double M[32][34];
    __shared__ double ua[32], ub[32];
    __shared__ float  cA[32], cB[32];

    const int b    = blockIdx.x;      // batch row
    const int tid  = threadIdx.x;     // 0..255
    const int lane = tid & 63;
    const int wv   = tid >> 6;        // 0..3

    const float gpv = gp[b];
    const float gvv = gv[b];

    af_sh[tid] = (tid < NH) ? Af[tid] : 0.f;
    x_sh[tid]  = (tid < NH) ? x[b * NH + tid] : 0.f;
    __syncthreads();

    // ---------------- Phase T: t_k = sum_{i>=k} Lq[i,k]*Af[i], 32-deep batches
    {
        float acc = 0.f;
        if (tid < NH) {
            for (int i0 = (tid & ~31); i0 < NH; i0 += 32) {
                float v[32];
                #pragma unroll
                for (int j = 0; j < 32; ++j) {
                    const int i = i0 + j;
                    v[j] = (i < NH) ? Lq[i * NH + tid] : 0.f;
                }
                #pragma unroll
                for (int j = 0; j < 32; ++j)
                    acc += v[j] * af_sh[i0 + j];     // index <= 255, safe
            }
        }
        t_sh[tid] = acc;
    }
    __syncthreads();

    // ---------------- Phase G: fused g-row reduce * x_b accumulate
    // wave wv covers rows 64*wv .. 64*wv+63 (rows >= NH contribute 0 via guards)
    {
        float sacc = 0.f;
        for (int r = 0; r < 64; r += 4) {
            float a4[4] = {0.f, 0.f, 0.f, 0.f};
            #pragma unroll
            for (int rr = 0; rr < 4; ++rr) {
                const int i = 64 * wv + r + rr;
                #pragma unroll
                for (int c = 0; c < 4; ++c) {
                    const int kk = lane + 64 * c;
                    const float lv = (i < NH && kk < NH) ? Lq[i * NH + kk] : 0.f;
                    a4[rr] += lv * t_sh[kk];
                }
            }
            #pragma unroll
            for (int rr = 0; rr < 4; ++rr) {
                #pragma unroll
                for (int off = 32; off; off >>= 1)
                    a4[rr] += __shfl_xor(a4[rr], off, 64);
            }
            #pragma unroll
            for (int rr = 0; rr < 4; ++rr) {
                const int i = 64 * wv + r + rr;      // < 256, LDS-safe
                sacc += x_sh[i] * (a4[rr] + FEPS * af_sh[i]);
            }
        }
        if (lane == 0) svals[wv] = sacc;
    }

    // ---------------- Phase S: fp64 scalar pipeline (proven) ----------------
    {
        double dv = 0.0;
        if (tid < NH) {
            const double td = (double)t_sh[tid];
            const double ad = (double)af_sh[tid];
            dv = td * td + DEPS * ad * ad;
        }
        #pragma unroll
        for (int off = 32; off; off >>= 1) dv += __shfl_xor(dv, off, 64);
        if (lane == 0) red[wv] = dv;
    }
    __syncthreads();
    const double c = red[0] + red[1] + red[2] + red[3];

    // Q_final: 1024 entries over 256 threads
    for (int e = tid; e < 1024; e += 256) {
        const int j1 = e >> 5, j2 = e & 31;
        const int m = (j1 > j2) ? j1 : j2;
        double s = 0.0;
        for (int kk = m; kk < 32; ++kk) {
            const double wk = (kk == 31) ? DPQ : 1.0;
            s += wk * ((double)(kk - j1) * (double)(kk - j2) * c + DQV);
        }
        M[j1][j2] = 2.0 * DDT * DDT * s + ((j1 == j2) ? (2.0 * DQA + DEPS) : 0.0);
    }
    // RHS: alpha (col 32), beta (col 33)
    if (tid < 32) {
        const int j = tid;
        double sa = 0.0, sb = 0.0;
        for (int kk = j; kk < 32; ++kk) {
            const double wk = (kk == 31) ? DPQ : 1.0;
            sa += wk * (double)(kk - j);
            sb += wk * ((double)(kk + 1) * (double)(kk - j) * c + DQV);
        }
        M[j][32] = 2.0 * DDT * sa;
        M[j][33] = 2.0 * DDT * sb;
    }
    __syncthreads();

    // Gauss-Jordan, no pivoting (SPD). Thread -> (row r, cols cg8+8k).
    {
        const int r   = tid & 31;
        const int cg8 = tid >> 5;    // 0..7
        for (int p = 0; p < 32; ++p) {
            const double f = M[r][p] / M[p][p];
            if (r != p) {
                for (int cc = cg8; cc < 34; cc += 8)
                    if (cc > p) M[r][cc] -= f * M[p][cc];
            }
            __syncthreads();
        }
    }
    if (tid < 32) {
        ua[tid] = -M[tid][32] / M[tid][tid];
        ub[tid] = -M[tid][33] / M[tid][tid];
    }
    __syncthreads();
    if (tid < 32) {
        const int i = tid;
        double ca = 0.0, cb = 0.0;
        for (int j = 0; j <= i; ++j) {
            const double wgt = (double)(i - j) + 0.5;
            ca += wgt * ua[j];
            cb += wgt * ub[j];
        }
        cA[i] = (float)(ca * DDT * DDT);                           // Calpha_i
        cB[i] = (float)((double)(i + 1) * DDT + cb * DDT * DDT);   // (i+1)dt+Cb_i
    }
    __syncthreads();

    // ---------------- Phase O: 32 outputs for batch row b
    if (tid < 32) {
        const float s = svals[0] + svals[1] + svals[2] + svals[3];
        out[b * NSTEP + tid] = gpv + gvv * cB[tid] + s * cA[tid];
    }
}

extern "C" void kernel_launch(void* const* d_in, const int* in_sizes, int n_in,
                              void* d_out, int out_size, void* d_ws, size_t ws_size,
                              hipStream_t stream) {
    const float* x  = (const float*)d_in[0];   // [256,254]
    const float* gp = (const float*)d_in[1];   // [256]
    const float* gv = (const float*)d_in[2];   // [256]
    // d_in[3] (other_gripper_v) unused by the forward path
    const float* Af = (const float*)d_in[4];   // [254]
    const float* Lq = (const float*)d_in[5];   // [254,254]
    float* out = (float*)d_out;                // [256,32]

    k_fused<<<NB, 256, 0, stream>>>(Lq, Af, x, gp, gv, out);
}

// Round 13
// 106.681 us; speedup vs baseline: 1.0006x; 1.0006x over previous
//
#include <hip/hip_runtime.h>

#define NH 254
#define NSTEP 32
#define NB 256

constexpr float  FEPS = 1e-4f;
constexpr double DDT  = 1.0 / 60.0;
constexpr double DQV  = 200.0;
constexpr double DPQ  = 5.0;
constexpr double DQA  = 1.0;
constexpr double DEPS = 1e-4;

// ---------------------------------------------------------------------------
// K1: 64 blocks x 256 threads. Block b owns batch rows 4b..4b+3.
// One sweep over Lq columns: thread k walks rows i (32-deep batches, triangle
// start at k&~31) computing
//   t_k    = sum_i Lq[i,k] * Af[i]          (written by block 0 only)
//   Y[r,k] = sum_i Lq[i,k] * x[r,i]         (4 rows per block)
// Y = X*Lq has NO dependence on t -> fully parallel, replaces serial g-phase:
//   s_b = x_b . g = Y_b . t + eps * (x_b . Af)
// ---------------------------------------------------------------------------
__global__ __launch_bounds__(256) void k_yt(const float* __restrict__ Lq,
                                            const float* __restrict__ Af,
                                            const float* __restrict__ x,
                                            float* __restrict__ Y,
                                            float* __restrict__ t_out) {
    __shared__ float af_sh[256];
    __shared__ float x_sh[4][256];
    const int k = threadIdx.x;
    const int b = blockIdx.x;          // 0..63

    af_sh[k] = (k < NH) ? Af[k] : 0.f;
    #pragma unroll
    for (int r = 0; r < 4; ++r) {
        const int row = 4 * b + r;     // 0..255
        x_sh[r][k] = (k < NH) ? x[row * NH + k] : 0.f;
    }
    __syncthreads();

    float ty = 0.f;
    float y0 = 0.f, y1 = 0.f, y2 = 0.f, y3 = 0.f;
    if (k < NH) {
        for (int i0 = (k & ~31); i0 < NH; i0 += 32) {
            float v[32];
            #pragma unroll
            for (int j = 0; j < 32; ++j) {
                const int i = i0 + j;
                v[j] = (i < NH) ? Lq[i * NH + k] : 0.f;
            }
            #pragma unroll
            for (int j = 0; j < 32; ++j) {
                const int i = i0 + j;          // <= 255, LDS-safe
                ty += v[j] * af_sh[i];
                y0 += v[j] * x_sh[0][i];
                y1 += v[j] * x_sh[1][i];
                y2 += v[j] * x_sh[2][i];
                y3 += v[j] * x_sh[3][i];
            }
        }
    }
    Y[(4 * b + 0) * 256 + k] = y0;
    Y[(4 * b + 1) * 256 + k] = y1;
    Y[(4 * b + 2) * 256 + k] = y2;
    Y[(4 * b + 3) * 256 + k] = y3;
    if (b == 0) t_out[k] = ty;         // zeros for k >= NH
}

// ---------------------------------------------------------------------------
// K2: ONE block, 256 threads. c = ||t||^2 + eps||Af||^2 -> Q_final (fp64) ->
// Gauss-Jordan (2 RHS) -> output coefficients cA/cB.  (Proven pipeline.)
// ---------------------------------------------------------------------------
__global__ __launch_bounds__(256) void k_solve(const float* __restrict__ t_in,
                                               const float* __restrict__ Af,
                                               float* __restrict__ coef) {
    __shared__ double red[4];
    __shared__ double M[32][34];
    __shared__ double ua[32], ub[32];

    const int tid  = threadIdx.x;
    const int lane = tid & 63;
    const int wv   = tid >> 6;

    {
        double dv = 0.0;
        if (tid < NH) {
            const double td = (double)t_in[tid];
            const double ad = (double)Af[tid];
            dv = td * td + DEPS * ad * ad;
        }
        #pragma unroll
        for (int off = 32; off; off >>= 1) dv += __shfl_xor(dv, off, 64);
        if (lane == 0) red[wv] = dv;
    }
    __syncthreads();
    const double c = red[0] + red[1] + red[2] + red[3];

    // Q_final: 1024 entries over 256 threads
    for (int e = tid; e < 1024; e += 256) {
        const int j1 = e >> 5, j2 = e & 31;
        const int m = (j1 > j2) ? j1 : j2;
        double s = 0.0;
        for (int kk = m; kk < 32; ++kk) {
            const double wk = (kk == 31) ? DPQ : 1.0;
            s += wk * ((double)(kk - j1) * (double)(kk - j2) * c + DQV);
        }
        M[j1][j2] = 2.0 * DDT * DDT * s + ((j1 == j2) ? (2.0 * DQA + DEPS) : 0.0);
    }
    // RHS: alpha (col 32), beta (col 33)
    if (tid < 32) {
        const int j = tid;
        double sa = 0.0, sb = 0.0;
        for (int kk = j; kk < 32; ++kk) {
            const double wk = (kk == 31) ? DPQ : 1.0;
            sa += wk * (double)(kk - j);
            sb += wk * ((double)(kk + 1) * (double)(kk - j) * c + DQV);
        }
        M[j][32] = 2.0 * DDT * sa;
        M[j][33] = 2.0 * DDT * sb;
    }
    __syncthreads();

    // Gauss-Jordan, no pivoting (SPD). Thread -> (row r, cols cg8 + 8k).
    {
        const int r   = tid & 31;
        const int cg8 = tid >> 5;    // 0..7
        for (int p = 0; p < 32; ++p) {
            const double f = M[r][p] / M[p][p];
            if (r != p) {
                for (int cc = cg8; cc < 34; cc += 8)
                    if (cc > p) M[r][cc] -= f * M[p][cc];
            }
            __syncthreads();
        }
    }
    if (tid < 32) {
        ua[tid] = -M[tid][32] / M[tid][tid];
        ub[tid] = -M[tid][33] / M[tid][tid];
    }
    __syncthreads();
    if (tid < 32) {
        const int i = tid;
        double ca = 0.0, cb = 0.0;
        for (int j = 0; j <= i; ++j) {
            const double wgt = (double)(i - j) + 0.5;
            ca += wgt * ua[j];
            cb += wgt * ub[j];
        }
        coef[i]      = (float)(ca * DDT * DDT);                          // cA_i
        coef[32 + i] = (float)((double)(i + 1) * DDT + cb * DDT * DDT);  // cB_i
    }
}

// ---------------------------------------------------------------------------
// K3: 256 blocks x 64 threads (one wave per batch row).
//   s_b = Y_b . t + eps * (x_b . Af);  out[b,i] = gp_b + gv_b*cB_i + s_b*cA_i
// 12 fully-independent loads per lane, one butterfly reduce.
// ---------------------------------------------------------------------------
__global__ __launch_bounds__(64) void k_out(const float* __restrict__ x,
                                            const float* __restrict__ gp,
                                            const float* __restrict__ gv,
                                            const float* __restrict__ Af,
                                            const float* __restrict__ Y,
                                            const float* __restrict__ t_in,
                                            const float* __restrict__ coef,
                                            float* __restrict__ out) {
    const int b    = blockIdx.x;
    const int lane = threadIdx.x;
    float acc = 0.f;
    #pragma unroll
    for (int c4 = 0; c4 < 4; ++c4) {
        const int kk = lane + 64 * c4;
        const float yv = Y[b * 256 + kk];           // zeros beyond NH
        const float tv = t_in[kk];                  // zeros beyond NH
        const float xv = (kk < NH) ? x[b * NH + kk] : 0.f;
        const float av = (kk < NH) ? Af[kk] : 0.f;
        acc += yv * tv + FEPS * xv * av;
    }
    #pragma unroll
    for (int off = 32; off; off >>= 1) acc += __shfl_xor(acc, off, 64);
    if (lane < 32)
        out[b * NSTEP + lane] = gp[b] + gv[b] * coef[32 + lane] + acc * coef[lane];
}

extern "C" void kernel_launch(void* const* d_in, const int* in_sizes, int n_in,
                              void* d_out, int out_size, void* d_ws, size_t ws_size,
                              hipStream_t stream) {
    const float* x  = (const float*)d_in[0];   // [256,254]
    const float* gp = (const float*)d_in[1];   // [256]
    const float* gv = (const float*)d_in[2];   // [256]
    // d_in[3] (other_gripper_v) unused by the forward path
    const float* Af = (const float*)d_in[4];   // [254]
    const float* Lq = (const float*)d_in[5];   // [254,254]
    float* out = (float*)d_out;                // [256,32]

    float* ws   = (float*)d_ws;
    float* Y    = ws;                  // 256*256 floats
    float* t    = ws + 256 * 256;      // 256 floats
    float* coef = t + 256;             // 64 floats

    k_yt   <<<64,  256, 0, stream>>>(Lq, Af, x, Y, t);
    k_solve<<<1,   256, 0, stream>>>(t, Af, coef);
    k_out  <<<NB,  64,  0, stream>>>(x, gp, gv, Af, Y, t, coef, out);
}